// Round 1
// baseline (823.524 us; speedup 1.0000x reference)
//
#include <hip/hip_runtime.h>

// Problem constants (reference: N=8192, DIN=DH=DOUT=64, SPARSITY=0.01)
#define NN 8192
#define DD 64

// Pass 1: build per-row CSR of w = left_weights * A.
// One block per row. Stream A (mandatory 256 MB read); only touch
// left_weights where the A float4-chunk has a nonzero (~4% of chunks),
// so lw HBM traffic is ~15% of cachelines instead of 100%.
__global__ __launch_bounds__(256) void build_csr_kernel(
    const float* __restrict__ A, const float* __restrict__ lw,
    int* __restrict__ cols, float* __restrict__ vals,
    int* __restrict__ cnt, int cap)
{
    const int r = blockIdx.x;
    __shared__ int scnt;
    if (threadIdx.x == 0) scnt = 0;
    __syncthreads();

    const float4* A4 = (const float4*)(A + (size_t)r * NN);
    const float4* L4 = (const float4*)(lw + (size_t)r * NN);
    const int base = r * cap;

    for (int i = threadIdx.x; i < NN / 4; i += blockDim.x) {
        float4 a = A4[i];
        if (a.x != 0.f || a.y != 0.f || a.z != 0.f || a.w != 0.f) {
            float4 l = L4[i];  // conditional load: only fetched for active lanes
            if (a.x != 0.f) { int p = atomicAdd(&scnt, 1); if (p < cap) { cols[base + p] = 4*i + 0; vals[base + p] = l.x; } }
            if (a.y != 0.f) { int p = atomicAdd(&scnt, 1); if (p < cap) { cols[base + p] = 4*i + 1; vals[base + p] = l.y; } }
            if (a.z != 0.f) { int p = atomicAdd(&scnt, 1); if (p < cap) { cols[base + p] = 4*i + 2; vals[base + p] = l.z; } }
            if (a.w != 0.f) { int p = atomicAdd(&scnt, 1); if (p < cap) { cols[base + p] = 4*i + 3; vals[base + p] = l.w; } }
        }
    }
    __syncthreads();
    if (threadIdx.x == 0) cnt[r] = (scnt < cap) ? scnt : cap;
}

// Pass 2 (x3 layers): y[r,:] = (sum_j vals[r,j] * x[cols[r,j], :]) @ W^T + b
// One 64-thread block (one wave) per row; thread t owns output dim t.
// x is 2 MB -> L2/LLC resident, gathers are cheap.
__global__ __launch_bounds__(64) void spmm_linear_kernel(
    const float* __restrict__ xin,
    const int* __restrict__ cols, const float* __restrict__ vals,
    const int* __restrict__ cnt, int cap,
    const float* __restrict__ W, const float* __restrict__ bias,
    float* __restrict__ xout)
{
    const int r = blockIdx.x;
    const int t = threadIdx.x;  // 0..63
    const int n = cnt[r];
    const int base = r * cap;

    float agg = 0.f;
    for (int j = 0; j < n; ++j) {
        const int   c = cols[base + j];  // wave-uniform broadcast load
        const float v = vals[base + j];
        agg += v * xin[c * DD + t];      // coalesced 256B row gather
    }

    __shared__ float sagg[DD];
    sagg[t] = agg;
    __syncthreads();

    const float* Wr = W + t * DD;  // W is [out,in] row-major; out dim t
    float acc = bias[t];
    #pragma unroll 8
    for (int k = 0; k < DD; ++k) acc += sagg[k] * Wr[k];
    xout[(size_t)r * DD + t] = acc;
}

extern "C" void kernel_launch(void* const* d_in, const int* in_sizes, int n_in,
                              void* d_out, int out_size, void* d_ws, size_t ws_size,
                              hipStream_t stream) {
    const float* x  = (const float*)d_in[0];
    const float* A  = (const float*)d_in[1];
    const float* lw = (const float*)d_in[2];
    const float* W0 = (const float*)d_in[3];
    const float* b0 = (const float*)d_in[4];
    const float* W1 = (const float*)d_in[5];
    const float* b1 = (const float*)d_in[6];
    const float* W2 = (const float*)d_in[7];
    const float* b2 = (const float*)d_in[8];
    float* out = (float*)d_out;

    // CSR capacity per row: mean nnz = 81.9, std = 9.0, max over 8192 rows
    // ~ 120. cap=256 is ~19 sigma of headroom. Shrink if ws is tight.
    auto need = [](size_t c) {
        return (size_t)NN * c * 8 + (size_t)NN * 4 + 2 * (size_t)NN * DD * 4;
    };
    int cap = 256;
    if (need(cap) > ws_size) cap = 192;
    if (need((size_t)cap) > ws_size) cap = 128;

    char* ws = (char*)d_ws;
    int*   cols = (int*)ws;   ws += (size_t)NN * cap * sizeof(int);
    float* vals = (float*)ws; ws += (size_t)NN * cap * sizeof(float);
    int*   cnt  = (int*)ws;   ws += (size_t)NN * sizeof(int);
    float* bufA = (float*)ws; ws += (size_t)NN * DD * sizeof(float);
    float* bufB = (float*)ws;

    // Pass 1: sparsify w = lw * A (cnt written unconditionally; no memset needed)
    build_csr_kernel<<<NN, 256, 0, stream>>>(A, lw, cols, vals, cnt, cap);

    // 3 layers: x -> bufA -> bufB -> out
    spmm_linear_kernel<<<NN, 64, 0, stream>>>(x,    cols, vals, cnt, cap, W0, b0, bufA);
    spmm_linear_kernel<<<NN, 64, 0, stream>>>(bufA, cols, vals, cnt, cap, W1, b1, bufB);
    spmm_linear_kernel<<<NN, 64, 0, stream>>>(bufB, cols, vals, cnt, cap, W2, b2, out);
}

// Round 2
// 586.765 us; speedup vs baseline: 1.4035x; 1.4035x over previous
//
#include <hip/hip_runtime.h>

// N=8192, DIN=DH=DOUT=64, SPARSITY=0.01 -> ~82 nnz/row (max ~122; cap 256 = 19 sigma)
#define NN 8192
#define DD 64
#define CAP 256

// Kernel 1: fused CSR build (w = lw * A, row-local) + layer 0.
// One 256-thread block per row. Streams A (mandatory 256 MB), touches lw only
// where the A-chunk is nonzero (~15% of cachelines), compacts (col,val) into
// LDS + global pairs (for layers 1/2), then does layer-0 aggregation + linear.
__global__ __launch_bounds__(256) void fused_build_l0_kernel(
    const float* __restrict__ A, const float* __restrict__ lw,
    const float* __restrict__ x,
    const float* __restrict__ W0, const float* __restrict__ b0,
    int2* __restrict__ pairs, int* __restrict__ cnt,
    float* __restrict__ y0)
{
    __shared__ int   scnt;
    __shared__ int   scols[CAP];
    __shared__ float svals[CAP];
    __shared__ float WT[DD * 65];      // transposed W0, pad 65 -> conflict-free
    __shared__ float partial[4][DD];
    __shared__ float ssum[DD];

    const int tid  = threadIdx.x;
    const int wave = tid >> 6;
    const int lane = tid & 63;
    const int r    = blockIdx.x;

    if (tid == 0) scnt = 0;
    // Stage W0^T: coalesced global read, padded LDS write (bank = (k+o)%32, free)
    for (int i = tid; i < DD * DD; i += 256)
        WT[(i & 63) * 65 + (i >> 6)] = W0[i];
    __syncthreads();

    const float4* A4 = (const float4*)(A + (size_t)r * NN);
    const float4* L4 = (const float4*)(lw + (size_t)r * NN);
    const int base = r * CAP;

    for (int i = tid; i < NN / 4; i += 256) {
        float4 a = A4[i];
        if (a.x != 0.f || a.y != 0.f || a.z != 0.f || a.w != 0.f) {
            float4 l = L4[i];  // fetched only when chunk has a nonzero
            #define EMIT(comp, off)                                                   \
                if (a.comp != 0.f) {                                                  \
                    int p = atomicAdd(&scnt, 1);                                      \
                    if (p < CAP) {                                                    \
                        scols[p] = 4 * i + off; svals[p] = l.comp;                    \
                        pairs[base + p] = make_int2(4 * i + off,                      \
                                                    __float_as_int(l.comp));          \
                    }                                                                 \
                }
            EMIT(x, 0) EMIT(y, 1) EMIT(z, 2) EMIT(w, 3)
            #undef EMIT
        }
    }
    __syncthreads();

    int n = scnt; if (n > CAP) n = CAP;
    if (tid == 0) cnt[r] = n;

    // Layer-0 aggregation: wave w takes j = w, w+4, ...; lane owns dim `lane`.
    float agg = 0.f;
    for (int j = wave; j < n; j += 4) {
        const int   c = scols[j];   // LDS broadcast
        const float v = svals[j];
        agg += v * x[(size_t)c * DD + lane];  // coalesced 256B gather, L2-resident
    }
    partial[wave][lane] = agg;
    __syncthreads();

    if (tid < DD) {
        ssum[lane] = partial[0][lane] + partial[1][lane]
                   + partial[2][lane] + partial[3][lane];
    }
    __syncthreads();

    if (tid < DD) {
        float acc = b0[lane];
        #pragma unroll 16
        for (int k = 0; k < DD; ++k)
            acc += ssum[k] * WT[k * 65 + lane];  // ssum broadcast, WT conflict-free
        y0[(size_t)r * DD + lane] = acc;
    }
}

// Kernel 2 (layers 1 and 2): 4 rows per 256-thread block, wave = row.
// 4-way j-parallel float4 gathers (lanes 0-15 -> j, 16-31 -> j+1, ...),
// shuffle-reduce across j-groups, then 64x64 linear from padded W^T in LDS.
__global__ __launch_bounds__(256) void layer_kernel(
    const float* __restrict__ xin,
    const int2* __restrict__ pairs, const int* __restrict__ cnt,
    const float* __restrict__ W, const float* __restrict__ bias,
    float* __restrict__ xout)
{
    __shared__ float WT[DD * 65];
    __shared__ float sagg[4 * DD];

    const int tid  = threadIdx.x;
    const int wave = tid >> 6;
    const int lane = tid & 63;
    const int grp  = lane >> 4;   // which of 4 concurrent j's
    const int l16  = lane & 15;   // float4 slice within the 64-dim row

    for (int i = tid; i < DD * DD; i += 256)
        WT[(i & 63) * 65 + (i >> 6)] = W[i];

    const int r    = blockIdx.x * 4 + wave;
    const int base = r * CAP;
    const int n    = cnt[r];

    const float4* xin4 = (const float4*)xin;
    float4 agg = make_float4(0.f, 0.f, 0.f, 0.f);
    for (int j = grp; j < n; j += 4) {
        int2  cv = pairs[base + j];        // one 8B load; 4 distinct addrs/wave
        float v  = __int_as_float(cv.y);
        float4 xv = xin4[(size_t)cv.x * (DD / 4) + l16];  // 1 KiB/wave-instr
        agg.x += v * xv.x; agg.y += v * xv.y;
        agg.z += v * xv.z; agg.w += v * xv.w;
    }
    // Reduce the 4 j-groups (lane^16 flips grp bit0, lane^32 flips bit1)
    agg.x += __shfl_xor(agg.x, 16); agg.y += __shfl_xor(agg.y, 16);
    agg.z += __shfl_xor(agg.z, 16); agg.w += __shfl_xor(agg.w, 16);
    agg.x += __shfl_xor(agg.x, 32); agg.y += __shfl_xor(agg.y, 32);
    agg.z += __shfl_xor(agg.z, 32); agg.w += __shfl_xor(agg.w, 32);

    if (grp == 0)
        *(float4*)&sagg[wave * DD + l16 * 4] = agg;
    __syncthreads();  // covers WT staging + sagg visibility

    float acc = bias[lane];
    #pragma unroll 16
    for (int k = 0; k < DD; ++k)
        acc += sagg[wave * DD + k] * WT[k * 65 + lane];
    xout[(size_t)r * DD + lane] = acc;
}

extern "C" void kernel_launch(void* const* d_in, const int* in_sizes, int n_in,
                              void* d_out, int out_size, void* d_ws, size_t ws_size,
                              hipStream_t stream) {
    const float* x  = (const float*)d_in[0];
    const float* A  = (const float*)d_in[1];
    const float* lw = (const float*)d_in[2];
    const float* W0 = (const float*)d_in[3];
    const float* b0 = (const float*)d_in[4];
    const float* W1 = (const float*)d_in[5];
    const float* b1 = (const float*)d_in[6];
    const float* W2 = (const float*)d_in[7];
    const float* b2 = (const float*)d_in[8];
    float* out = (float*)d_out;

    char* ws = (char*)d_ws;
    int2*  pairs = (int2*)ws;  ws += (size_t)NN * CAP * sizeof(int2);   // 16 MB
    int*   cnt   = (int*)ws;   ws += (size_t)NN * sizeof(int);
    float* bufA  = (float*)ws; ws += (size_t)NN * DD * sizeof(float);
    float* bufB  = (float*)ws;

    // Layer 0 fused with CSR build (row-local dependency only)
    fused_build_l0_kernel<<<NN, 256, 0, stream>>>(A, lw, x, W0, b0, pairs, cnt, bufA);
    // Layers 1, 2 (need global sync between -> separate dispatches)
    layer_kernel<<<NN / 4, 256, 0, stream>>>(bufA, pairs, cnt, W1, b1, bufB);
    layer_kernel<<<NN / 4, 256, 0, stream>>>(bufB, pairs, cnt, W2, b2, out);
}

// Round 3
// 540.214 us; speedup vs baseline: 1.5244x; 1.0862x over previous
//
#include <hip/hip_runtime.h>

// N=8192, DIN=DH=DOUT=64, SPARSITY=0.01 -> ~82 nnz/row (max ~122; CAP=256 = 19 sigma)
#define NN 8192
#define DD 64
#define CAP 256
#define CHUNKS 8  // (NN/4) / 256 threads

// Kernel 1: fused CSR build (w = lw * A) + layer 0.
// One 256-thread block per row. All 8 A-chunks batched into registers
// (8 KiB/wave in flight), lw chunks batch-loaded under predicate,
// then 16-way j-parallel float4-gather aggregation + 64x64 linear.
__global__ __launch_bounds__(256) void fused_build_l0_kernel(
    const float* __restrict__ A, const float* __restrict__ lw,
    const float* __restrict__ x,
    const float* __restrict__ W0, const float* __restrict__ b0,
    int2* __restrict__ pairs, int* __restrict__ cnt,
    float* __restrict__ y0)
{
    __shared__ int    scnt;
    __shared__ int    scols[CAP];
    __shared__ float  svals[CAP];
    __shared__ float  WT[DD * 65];     // W0^T, +1 pad -> conflict-free
    __shared__ float4 partial[4][16];
    __shared__ float  ssum[DD];

    const int tid  = threadIdx.x;
    const int wave = tid >> 6;
    const int lane = tid & 63;
    const int grp  = lane >> 4;        // 4 j-groups per wave
    const int l16  = lane & 15;        // float4 slice of the 64-dim row
    const int g    = wave * 4 + grp;   // 0..15 j-groups per block
    const int r    = blockIdx.x;

    if (tid == 0) scnt = 0;
    for (int i = tid; i < DD * DD; i += 256)
        WT[(i & 63) * 65 + (i >> 6)] = W0[i];
    __syncthreads();

    const float4* A4 = (const float4*)(A + (size_t)r * NN);
    const float4* L4 = (const float4*)(lw + (size_t)r * NN);
    const int base = r * CAP;

    // Batched unconditional A loads: 8 global_load_dwordx4 issued back-to-back.
    float4 a[CHUNKS];
    #pragma unroll
    for (int k = 0; k < CHUNKS; ++k) a[k] = A4[tid + 256 * k];

    bool nz[CHUNKS];
    #pragma unroll
    for (int k = 0; k < CHUNKS; ++k)
        nz[k] = (a[k].x != 0.f) || (a[k].y != 0.f) || (a[k].z != 0.f) || (a[k].w != 0.f);

    // Batched predicated lw loads (~4% of chunks active; exec-masked, all in flight).
    float4 l[CHUNKS];
    #pragma unroll
    for (int k = 0; k < CHUNKS; ++k)
        if (nz[k]) l[k] = L4[tid + 256 * k];

    #pragma unroll
    for (int k = 0; k < CHUNKS; ++k) {
        if (nz[k]) {
            const int cbase = 4 * (tid + 256 * k);
            #define EMIT(comp, off)                                               \
                if (a[k].comp != 0.f) {                                           \
                    int p = atomicAdd(&scnt, 1);                                  \
                    if (p < CAP) {                                                \
                        scols[p] = cbase + off; svals[p] = l[k].comp;             \
                        pairs[base + p] =                                         \
                            make_int2(cbase + off, __float_as_int(l[k].comp));    \
                    }                                                             \
                }
            EMIT(x, 0) EMIT(y, 1) EMIT(z, 2) EMIT(w, 3)
            #undef EMIT
        }
    }
    __syncthreads();

    int n = scnt; if (n > CAP) n = CAP;
    if (tid == 0) cnt[r] = n;
    const int nr = (n + 15) & ~15;           // pad to x16 -> branch-free j-loop
    if (tid >= n && tid < nr) { scols[tid] = 0; svals[tid] = 0.f; }
    __syncthreads();

    // 16-way j-parallel aggregation; gathers independent across j, all in flight.
    const float4* x4 = (const float4*)x;
    float4 agg = make_float4(0.f, 0.f, 0.f, 0.f);
    for (int j = g; j < nr; j += 16) {
        const int   c = scols[j];            // LDS broadcast within group
        const float v = svals[j];
        float4 xv = x4[(size_t)c * (DD / 4) + l16];  // 256B/group, L2-resident
        agg.x += v * xv.x; agg.y += v * xv.y;
        agg.z += v * xv.z; agg.w += v * xv.w;
    }
    agg.x += __shfl_xor(agg.x, 16); agg.y += __shfl_xor(agg.y, 16);
    agg.z += __shfl_xor(agg.z, 16); agg.w += __shfl_xor(agg.w, 16);
    agg.x += __shfl_xor(agg.x, 32); agg.y += __shfl_xor(agg.y, 32);
    agg.z += __shfl_xor(agg.z, 32); agg.w += __shfl_xor(agg.w, 32);
    if (grp == 0) partial[wave][l16] = agg;
    __syncthreads();

    if (tid < DD) {
        const float* pf = (const float*)partial;   // [4][64] floats
        ssum[tid] = pf[tid] + pf[64 + tid] + pf[128 + tid] + pf[192 + tid];
    }
    __syncthreads();

    if (tid < DD) {
        float acc = b0[tid];
        #pragma unroll 16
        for (int k = 0; k < DD; ++k)
            acc += ssum[k] * WT[k * 65 + tid];
        y0[(size_t)r * DD + tid] = acc;
    }
}

// Kernel 2 (layers 1, 2): 4 rows per 256-thread block, wave = row.
// Pairs LDS-staged (removes pair load from critical path), zero-padded to x16,
// inner loop batches 4 independent float4 gathers per group.
__global__ __launch_bounds__(256) void layer_kernel(
    const float* __restrict__ xin,
    const int2* __restrict__ pairs, const int* __restrict__ cnt,
    const float* __restrict__ W, const float* __restrict__ bias,
    float* __restrict__ xout)
{
    __shared__ float  WT[DD * 65];
    __shared__ int2   spairs[4][CAP];
    __shared__ float4 sagg[4][16];

    const int tid  = threadIdx.x;
    const int wave = tid >> 6;
    const int lane = tid & 63;
    const int grp  = lane >> 4;
    const int l16  = lane & 15;

    for (int i = tid; i < DD * DD; i += 256)
        WT[(i & 63) * 65 + (i >> 6)] = W[i];

    const int r    = blockIdx.x * 4 + wave;
    const int base = r * CAP;
    const int n    = cnt[r];
    const int nr   = (n + 15) & ~15;

    for (int j = lane; j < n; j += 64) spairs[wave][j] = pairs[base + j];
    for (int j = n + lane; j < nr; j += 64) spairs[wave][j] = make_int2(0, 0);
    __syncthreads();

    const float4* x4 = (const float4*)xin;
    float4 agg = make_float4(0.f, 0.f, 0.f, 0.f);
    for (int j0 = grp * 4; j0 < nr; j0 += 16) {   // group takes 4 consecutive j
        int2 cv[4];
        #pragma unroll
        for (int t = 0; t < 4; ++t) cv[t] = spairs[wave][j0 + t];
        float4 xv[4];
        #pragma unroll
        for (int t = 0; t < 4; ++t)
            xv[t] = x4[(size_t)cv[t].x * (DD / 4) + l16];  // 4 gathers in flight
        #pragma unroll
        for (int t = 0; t < 4; ++t) {
            const float v = __int_as_float(cv[t].y);
            agg.x += v * xv[t].x; agg.y += v * xv[t].y;
            agg.z += v * xv[t].z; agg.w += v * xv[t].w;
        }
    }
    agg.x += __shfl_xor(agg.x, 16); agg.y += __shfl_xor(agg.y, 16);
    agg.z += __shfl_xor(agg.z, 16); agg.w += __shfl_xor(agg.w, 16);
    agg.x += __shfl_xor(agg.x, 32); agg.y += __shfl_xor(agg.y, 32);
    agg.z += __shfl_xor(agg.z, 32); agg.w += __shfl_xor(agg.w, 32);
    if (grp == 0) sagg[wave][l16] = agg;
    __syncthreads();

    const float* sa = (const float*)&sagg[wave][0];
    float acc = bias[lane];
    #pragma unroll 16
    for (int k = 0; k < DD; ++k)
        acc += sa[k] * WT[k * 65 + lane];
    xout[(size_t)r * DD + lane] = acc;
}

extern "C" void kernel_launch(void* const* d_in, const int* in_sizes, int n_in,
                              void* d_out, int out_size, void* d_ws, size_t ws_size,
                              hipStream_t stream) {
    const float* x  = (const float*)d_in[0];
    const float* A  = (const float*)d_in[1];
    const float* lw = (const float*)d_in[2];
    const float* W0 = (const float*)d_in[3];
    const float* b0 = (const float*)d_in[4];
    const float* W1 = (const float*)d_in[5];
    const float* b1 = (const float*)d_in[6];
    const float* W2 = (const float*)d_in[7];
    const float* b2 = (const float*)d_in[8];
    float* out = (float*)d_out;

    char* ws = (char*)d_ws;
    int2*  pairs = (int2*)ws;  ws += (size_t)NN * CAP * sizeof(int2);  // 16 MB
    int*   cnt   = (int*)ws;   ws += (size_t)NN * sizeof(int);
    float* bufA  = (float*)ws; ws += (size_t)NN * DD * sizeof(float);
    float* bufB  = (float*)ws;

    fused_build_l0_kernel<<<NN, 256, 0, stream>>>(A, lw, x, W0, b0, pairs, cnt, bufA);
    layer_kernel<<<NN / 4, 256, 0, stream>>>(bufA, pairs, cnt, W1, b1, bufB);
    layer_kernel<<<NN / 4, 256, 0, stream>>>(bufB, pairs, cnt, W2, b2, out);
}

// Round 4
// 537.451 us; speedup vs baseline: 1.5323x; 1.0051x over previous
//
#include <hip/hip_runtime.h>

// N=8192, DIN=DH=DOUT=64, SPARSITY=0.01 -> ~82 nnz/row, ~41/half-row
// (half-row nnz ~ Binom(4096,0.01): mean 41, std 6.4; CAPH=128 = 13.6 sigma)
#define NN 8192
#define DD 64
#define CAP 256   // per-row slab (two halves)
#define CAPH 128  // per half-row slab

// Pure streaming scan: one 256-thread block per HALF-row (grid 16384).
// 4 unconditional float4 A-loads/thread (4 KiB/wave in flight), predicated lw
// loads, LDS compaction, one coalesced slab write. No global atomics.
__global__ __launch_bounds__(256) void scan_kernel(
    const float* __restrict__ A, const float* __restrict__ lw,
    int2* __restrict__ pairs, int* __restrict__ cnt2)
{
    __shared__ int   scnt;
    __shared__ int   scols[CAPH];
    __shared__ float svals[CAPH];

    const int tid = threadIdx.x;
    const int r   = blockIdx.x >> 1;
    const int bh  = blockIdx.x & 1;

    if (tid == 0) scnt = 0;
    __syncthreads();

    const float4* A4 = (const float4*)(A + (size_t)r * NN) + bh * 1024;
    const float4* L4 = (const float4*)(lw + (size_t)r * NN) + bh * 1024;

    float4 a[4];
    #pragma unroll
    for (int k = 0; k < 4; ++k) a[k] = A4[tid + 256 * k];

    bool nz[4];
    #pragma unroll
    for (int k = 0; k < 4; ++k)
        nz[k] = (a[k].x != 0.f) || (a[k].y != 0.f) || (a[k].z != 0.f) || (a[k].w != 0.f);

    float4 l[4];
    #pragma unroll
    for (int k = 0; k < 4; ++k)
        if (nz[k]) l[k] = L4[tid + 256 * k];   // ~4% of chunks; exec-masked

    #pragma unroll
    for (int k = 0; k < 4; ++k) {
        if (nz[k]) {
            const int cbase = 4 * (bh * 1024 + tid + 256 * k);
            #define EMIT(comp, off)                                         \
                if (a[k].comp != 0.f) {                                     \
                    int p = atomicAdd(&scnt, 1);                            \
                    if (p < CAPH) { scols[p] = cbase + off;                 \
                                    svals[p] = l[k].comp; }                 \
                }
            EMIT(x, 0) EMIT(y, 1) EMIT(z, 2) EMIT(w, 3)
            #undef EMIT
        }
    }
    __syncthreads();

    int n = scnt; if (n > CAPH) n = CAPH;
    if (tid == 0) cnt2[blockIdx.x] = n;
    if (tid < n)  // one coalesced 8B-per-lane burst
        pairs[(size_t)r * CAP + bh * CAPH + tid] =
            make_int2(scols[tid], __float_as_int(svals[tid]));
}

// Layer pass (x3): 4 rows per 256-thread block, wave = row.
// Two half-slabs staged into LDS, zero-padded to x16, 16-way j-parallel
// batched float4 gathers, shuffle-reduce, 64x64 linear from padded W^T.
__global__ __launch_bounds__(256) void layer_kernel(
    const float* __restrict__ xin,
    const int2* __restrict__ pairs, const int* __restrict__ cnt2,
    const float* __restrict__ W, const float* __restrict__ bias,
    float* __restrict__ xout)
{
    __shared__ float  WT[DD * 65];
    __shared__ int2   spairs[4][CAP];
    __shared__ float4 sagg[4][16];

    const int tid  = threadIdx.x;
    const int wave = tid >> 6;
    const int lane = tid & 63;
    const int grp  = lane >> 4;
    const int l16  = lane & 15;

    for (int i = tid; i < DD * DD; i += 256)
        WT[(i & 63) * 65 + (i >> 6)] = W[i];

    const int r  = blockIdx.x * 4 + wave;
    const int n0 = cnt2[2 * r];
    const int n1 = cnt2[2 * r + 1];
    const int n  = n0 + n1;
    const int nr = (n + 15) & ~15;
    const size_t base = (size_t)r * CAP;

    for (int j = lane; j < n0; j += 64) spairs[wave][j]      = pairs[base + j];
    for (int j = lane; j < n1; j += 64) spairs[wave][n0 + j] = pairs[base + CAPH + j];
    for (int j = n + lane; j < nr; j += 64) spairs[wave][j]  = make_int2(0, 0);
    __syncthreads();

    const float4* x4 = (const float4*)xin;
    float4 agg = make_float4(0.f, 0.f, 0.f, 0.f);
    for (int j0 = grp * 4; j0 < nr; j0 += 16) {
        int2 cv[4];
        #pragma unroll
        for (int t = 0; t < 4; ++t) cv[t] = spairs[wave][j0 + t];
        float4 xv[4];
        #pragma unroll
        for (int t = 0; t < 4; ++t)
            xv[t] = x4[(size_t)cv[t].x * (DD / 4) + l16];  // 4 gathers in flight
        #pragma unroll
        for (int t = 0; t < 4; ++t) {
            const float v = __int_as_float(cv[t].y);
            agg.x += v * xv[t].x; agg.y += v * xv[t].y;
            agg.z += v * xv[t].z; agg.w += v * xv[t].w;
        }
    }
    agg.x += __shfl_xor(agg.x, 16); agg.y += __shfl_xor(agg.y, 16);
    agg.z += __shfl_xor(agg.z, 16); agg.w += __shfl_xor(agg.w, 16);
    agg.x += __shfl_xor(agg.x, 32); agg.y += __shfl_xor(agg.y, 32);
    agg.z += __shfl_xor(agg.z, 32); agg.w += __shfl_xor(agg.w, 32);
    if (grp == 0) sagg[wave][l16] = agg;
    __syncthreads();

    const float* sa = (const float*)&sagg[wave][0];
    float acc = bias[lane];
    #pragma unroll 16
    for (int k = 0; k < DD; ++k)
        acc += sa[k] * WT[k * 65 + lane];
    xout[(size_t)r * DD + lane] = acc;
}

extern "C" void kernel_launch(void* const* d_in, const int* in_sizes, int n_in,
                              void* d_out, int out_size, void* d_ws, size_t ws_size,
                              hipStream_t stream) {
    const float* x  = (const float*)d_in[0];
    const float* A  = (const float*)d_in[1];
    const float* lw = (const float*)d_in[2];
    const float* W0 = (const float*)d_in[3];
    const float* b0 = (const float*)d_in[4];
    const float* W1 = (const float*)d_in[5];
    const float* b1 = (const float*)d_in[6];
    const float* W2 = (const float*)d_in[7];
    const float* b2 = (const float*)d_in[8];
    float* out = (float*)d_out;

    char* ws = (char*)d_ws;
    int2*  pairs = (int2*)ws;  ws += (size_t)NN * CAP * sizeof(int2);  // 16 MB
    int*   cnt2  = (int*)ws;   ws += (size_t)2 * NN * sizeof(int);
    float* bufA  = (float*)ws; ws += (size_t)NN * DD * sizeof(float);
    float* bufB  = (float*)ws;

    scan_kernel<<<2 * NN, 256, 0, stream>>>(A, lw, pairs, cnt2);
    layer_kernel<<<NN / 4, 256, 0, stream>>>(x,    pairs, cnt2, W0, b0, bufA);
    layer_kernel<<<NN / 4, 256, 0, stream>>>(bufA, pairs, cnt2, W1, b1, bufB);
    layer_kernel<<<NN / 4, 256, 0, stream>>>(bufB, pairs, cnt2, W2, b2, out);
}